// Round 7
// baseline (315.364 us; speedup 1.0000x reference)
//
#include <hip/hip_runtime.h>
#include <math.h>

typedef __attribute__((ext_vector_type(2))) float f32x2;
typedef __attribute__((ext_vector_type(4))) float f32x4;

#define MAX_DELAY 128
#define INPUT 64
#define HIDDEN 128
#define HALF 64
#define OUT 64
#define BATCH 32
#define T 128
#define OUT_LEN 64
#define NTHR 512

static __device__ __forceinline__ f32x2 splat2(float v) { f32x2 r; r.x = v; r.y = v; return r; }
static __device__ __forceinline__ f32x4 splat4(float v) { f32x4 r; r.x = v; r.y = v; r.z = v; r.w = v; return r; }

// ---- packed-FP32 VOP3P (CDNA dual-fp32). Compiler scalarizes f32x2 math to
// v_fma_f32 pairs; these force v_pk_* (half the issue slots). Non-volatile,
// register-only: scheduler can move them freely. ----
static __device__ __forceinline__ f32x2 pk_fma(f32x2 a, f32x2 b, f32x2 c) {
    f32x2 d;
    asm("v_pk_fma_f32 %0, %1, %2, %3" : "=v"(d) : "v"(a), "v"(b), "v"(c));
    return d;
}
static __device__ __forceinline__ f32x2 pk_fma_n0(f32x2 a, f32x2 b, f32x2 c) { // -a*b + c
    f32x2 d;
    asm("v_pk_fma_f32 %0, %1, %2, %3 neg_lo:[1,0,0] neg_hi:[1,0,0]"
        : "=v"(d) : "v"(a), "v"(b), "v"(c));
    return d;
}
static __device__ __forceinline__ f32x2 pk_add(f32x2 a, f32x2 b) {
    f32x2 d;
    asm("v_pk_add_f32 %0, %1, %2" : "=v"(d) : "v"(a), "v"(b));
    return d;
}
static __device__ __forceinline__ f32x2 lo2(f32x4 v) { f32x2 r; r.x = v.x; r.y = v.y; return r; }
static __device__ __forceinline__ f32x2 hi2(f32x4 v) { f32x2 r; r.x = v.z; r.y = v.w; return r; }

// packed dot: N f32x4 weight regs (by-ref array: SROA keeps in VGPRs) . N f32x4 from LDS
template <int N>
static __device__ __forceinline__ float dotN(const f32x4 (&w)[N], const f32x4* v) {
    f32x2 a0 = splat2(0.f), a1 = splat2(0.f), a2 = splat2(0.f), a3 = splat2(0.f);
#pragma unroll
    for (int j = 0; j < N; ++j) {
        const f32x4 wv = w[j], vv = v[j];
        if (j & 1) { a2 = pk_fma(lo2(wv), lo2(vv), a2); a3 = pk_fma(hi2(wv), hi2(vv), a3); }
        else       { a0 = pk_fma(lo2(wv), lo2(vv), a0); a1 = pk_fma(hi2(wv), hi2(vv), a1); }
    }
    const f32x2 s = pk_add(pk_add(a0, a1), pk_add(a2, a3));
    return s.x + s.y;
}

// DPP cross-lane (1-cycle VALU).
template <int CTRL>
static __device__ __forceinline__ float dpp_movf(float v) {
    return __int_as_float(__builtin_amdgcn_update_dpp(
        0, __float_as_int(v), CTRL, 0xF, 0xF, true));
}
#define DPP_XOR1 0xB1  // quad_perm [1,0,3,2]
#define DPP_XOR2 0x4E  // quad_perm [2,3,0,1]
#define DPP_ROT1 0x39  // quad_perm [1,2,3,0] (lane i <- i+1 mod 4)
#define DPP_MIR8 0x141 // row_half_mirror

// msg LDS pad: stride-24 per 16 floats (conflict-free, x4-aligned)
#define PAD16(k) ((k) + (((k) >> 4) << 3))
// heads LDS pad: +4 floats per 32 -> quad streams hit disjoint bank groups
#define PADH(k)  ((k) + (((k) >> 5) << 2))

// R6 structure (best: 243.9 us) with all GEMV dots + blend forced to packed
// FP32 (v_pk_fma_f32) via inline asm: ~130 VALU inst/wave/iter removed.
__global__ __attribute__((amdgpu_waves_per_eu(2, 2))) __launch_bounds__(NTHR)
void delayrnn_kernel(
    const float* __restrict__ x,        // (B, T, INPUT)
    const int*   __restrict__ lengths,  // (B)
    const float* __restrict__ Wm,       // (INPUT+HIDDEN, HIDDEN)
    const float* __restrict__ bm,       // (HIDDEN)
    const float* __restrict__ W1,       // (HIDDEN, HALF)
    const float* __restrict__ b1,       // (HALF)
    const float* __restrict__ W2,       // (HALF, 2*HIDDEN)
    const float* __restrict__ b2,       // (2*HIDDEN)
    const float* __restrict__ Wo,       // (HIDDEN, OUT)
    const float* __restrict__ bo,       // (OUT)
    float* __restrict__ out)            // (B, OUT_LEN, OUT)
{
    const int b   = blockIdx.x;
    const int tid = threadIdx.x;
    const int len = lengths[b];
    const int total = len + OUT_LEN;

    const int h  = tid >> 2, q  = tid & 3;   // channel h: quad of 4 lanes
    const int qq = q & 1,    qh = q >> 1;    // tau/mem roles within the quad
    const int k1 = tid >> 3, r1 = tid & 7;   // h1: 8 lanes/out
    const int co = tid >> 3, ro = tid & 7;   // out-proj: 8 lanes/out
    const int c2 = h + 128 * qh;             // qh=0: tau col, qh=1: mem col

    // ---- weights -> registers (all f32) ----
    f32x4 wmh[8];                       // msg heads-part: rows 64 + [q*32, q*32+32)
#pragma unroll
    for (int j = 0; j < 8; ++j) {
        wmh[j].x = Wm[(64 + q * 32 + 4 * j    ) * HIDDEN + h];
        wmh[j].y = Wm[(64 + q * 32 + 4 * j + 1) * HIDDEN + h];
        wmh[j].z = Wm[(64 + q * 32 + 4 * j + 2) * HIDDEN + h];
        wmh[j].w = Wm[(64 + q * 32 + 4 * j + 3) * HIDDEN + h];
    }
    f32x4 wmx[4];                       // msg x-part: rows [q*16, q*16+16)
#pragma unroll
    for (int j = 0; j < 4; ++j) {
        wmx[j].x = Wm[(q * 16 + 4 * j    ) * HIDDEN + h];
        wmx[j].y = Wm[(q * 16 + 4 * j + 1) * HIDDEN + h];
        wmx[j].z = Wm[(q * 16 + 4 * j + 2) * HIDDEN + h];
        wmx[j].w = Wm[(q * 16 + 4 * j + 3) * HIDDEN + h];
    }
    f32x4 w14[4];                       // h1: K-slice [r1*16, r1*16+16)
#pragma unroll
    for (int j = 0; j < 4; ++j) {
        w14[j].x = W1[(r1 * 16 + 4 * j    ) * HALF + k1];
        w14[j].y = W1[(r1 * 16 + 4 * j + 1) * HALF + k1];
        w14[j].z = W1[(r1 * 16 + 4 * j + 2) * HALF + k1];
        w14[j].w = W1[(r1 * 16 + 4 * j + 3) * HALF + k1];
    }
    f32x4 w24[8];                       // tau/mem: K-slice [qq*32, qq*32+32)
#pragma unroll
    for (int j = 0; j < 8; ++j) {
        w24[j].x = W2[(qq * 32 + 4 * j    ) * (2 * HIDDEN) + c2];
        w24[j].y = W2[(qq * 32 + 4 * j + 1) * (2 * HIDDEN) + c2];
        w24[j].z = W2[(qq * 32 + 4 * j + 2) * (2 * HIDDEN) + c2];
        w24[j].w = W2[(qq * 32 + 4 * j + 3) * (2 * HIDDEN) + c2];
    }
    f32x4 wo4[4];                       // out: K-slice [ro*16, ro*16+16)
#pragma unroll
    for (int m = 0; m < 4; ++m) {
        wo4[m].x = Wo[(ro * 16 + 4 * m    ) * OUT + co];
        wo4[m].y = Wo[(ro * 16 + 4 * m + 1) * OUT + co];
        wo4[m].z = Wo[(ro * 16 + 4 * m + 2) * OUT + co];
        wo4[m].w = Wo[(ro * 16 + 4 * m + 3) * OUT + co];
    }
    const float bm_r = bm[h];
    const float b1_r = b1[k1];
    const float b2_r = b2[c2];
    const float bo_r = bo[co];

    // delay-buffer slice: channel h, delays q*32 .. q*32+31
    f32x2 buf2[16];
#pragma unroll
    for (int d = 0; d < 16; ++d) { buf2[d].x = 0.f; buf2[d].y = 0.f; }

    __shared__ f32x4 s_x4[T * INPUT / 4];   // 32 KB staged input
    __shared__ float s_vh[140];             // heads, PADH layout (conflict-free)
    __shared__ f32x4 s_msg4[48];            // msg f32, stride-24 per 16
    __shared__ float s_h1[HALF];
    __shared__ f32x4 s_out4[OUT_LEN * OUT / 4];  // 16 KB decode-output stash

    {
        const f32x4* xg4 = (const f32x4*)x;
        for (int idx = tid; idx < T * INPUT / 4; idx += NTHR)
            s_x4[idx] = xg4[b * (T * INPUT / 4) + idx];
        if (tid < 35) ((f32x4*)s_vh)[tid] = splat4(0.f);   // heads = 0 (140 floats)
    }
    __syncthreads();                        // B1 (iter 0)

    // preamble: x-part partial for step 0
    float px = 0.f;
    if (0 < len) px = dotN<4>(wmx, s_x4 + q * 4);

    const float ivb = (float)q * 0.25f;     // (q*32)/128
    float msg_p = 0.f, tau_p = 0.f, mem_p = 0.f;  // deferred-blend state (i=0: no-op)

    for (int i = 0; i < total; ++i) {
        // ============ phase 1: heads dot (+ deferred blend of step i-1) ============
        const f32x4* v4 = (const f32x4*)(s_vh + q * 36);
        const float pdot = dotN<8>(wmh, v4);

        // ---- deferred blend of step i-1 (packed; fills the LDS-read stall) ----
        {
            float tail_in = dpp_movf<DPP_ROT1>(buf2[0].x);   // neighbor q+1's old head
            if (q == 3) tail_in = 0.f;                       // shift-in zero at d=127
            const float taup = tau_p - ivb;
            f32x2 t2; t2.x = taup; t2.y = taup - (1.f / MAX_DELAY);
            const f32x2 st2  = splat2(-2.f / MAX_DELAY);
            const f32x2 mem2 = splat2(mem_p);
            const f32x2 m2m  = splat2(-2.f * mem_p);
            const f32x2 msg2 = splat2(msg_p);
#pragma unroll
            for (int d = 0; d < 16; ++d) {
                f32x2 nb;
                nb.x = buf2[d].y;
                nb.y = (d < 15) ? buf2[d + 1].x : tail_in;
                f32x2 a  = __builtin_elementwise_max(t2, -t2);   // |tau' - d/128|
                f32x2 f1 = pk_fma(a, mem2, m2m);                 // a*mem - 2mem
                f32x2 iw = pk_fma(a, f1, mem2);                  // mem*(1-a)^2
                f32x2 u  = pk_fma(iw, msg2, nb);                 // iw*msg + nb
                buf2[d]  = pk_fma_n0(iw, nb, u);                 // -iw*nb + u = nb + iw*(msg-nb)
                t2 = pk_add(t2, st2);
            }
        }

        float p = pdot + px;                        // + lookahead x-part
        p += dpp_movf<DPP_XOR1>(p);
        p += dpp_movf<DPP_XOR2>(p);                 // all 4 lanes: full K=192 dot
        const float z  = p + bm_r;
        const float e2 = __expf(2.f * z);
        const float msg = 1.f - 2.f * __builtin_amdgcn_rcpf(e2 + 1.f);  // tanh
        if (q == 0) ((float*)s_msg4)[PAD16(h)] = msg;
        msg_p = msg;
        __syncthreads();                            // B2: msg visible block-wide

        // ============ phase 2: h1 + x-lookahead + out-stash ============
        {
            const f32x4* m4 = (const f32x4*)((const float*)s_msg4 + r1 * 24);
            float p1 = dotN<4>(w14, m4);
            p1 += dpp_movf<DPP_XOR1>(p1);
            p1 += dpp_movf<DPP_XOR2>(p1);
            p1 += dpp_movf<DPP_MIR8>(p1);           // 8-lane allreduce
            if (r1 == 0) s_h1[k1] = fmaxf(p1 + b1_r, 0.f);
        }

        // ---- x-part lookahead for step i+1 (independent; fills h1 stall) ----
        px = 0.f;
        if (i + 1 < len) px = dotN<4>(wmx, s_x4 + (i + 1) * 16 + q * 4);

        // ---- decode out-projection -> LDS stash (no global store in loop) ----
        if (i >= len) {
            const f32x4* mo4 = (const f32x4*)((const float*)s_msg4 + ro * 24);
            float po = dotN<4>(wo4, mo4);
            po += dpp_movf<DPP_XOR1>(po);
            po += dpp_movf<DPP_XOR2>(po);
            po += dpp_movf<DPP_MIR8>(po);
            if (ro == 0) ((float*)s_out4)[(i - len) * OUT + co] = po + bo_r;
        }
        __syncthreads();                            // B3: h1 visible block-wide

        // ============ phase 3: tau/mem + head only (blend deferred) ============
        {
            const f32x4* hh4 = (const f32x4*)(s_h1 + (qq << 5));
            float pt = dotN<8>(w24, hh4);
            pt += dpp_movf<DPP_XOR1>(pt);            // K-halves combined
            const float own = __builtin_amdgcn_rcpf(1.f + __expf(-(pt + b2_r)));
            const float oth = dpp_movf<DPP_XOR2>(own);
            const float tau_r = qh ? oth : own;
            const float mem_r = qh ? own : oth;
            tau_p = tau_r; mem_p = mem_r;

            // head (global delay 0) from post-blend(i-1) buf[1]; full blend deferred
            const float nb0 = buf2[0].y;
            const float iw0 = tau_r * (tau_r * mem_r - 2.f * mem_r) + mem_r;  // mem*(1-tau)^2
            const float head = iw0 * (msg_p - nb0) + nb0;
            if (q == 0) s_vh[PADH(h)] = head;
        }
        __syncthreads();                            // B1 (next iter)
    }

    // ---- bulk store decode outputs (coalesced) ----
    {
        f32x4* og4 = (f32x4*)(out + b * OUT_LEN * OUT);
        og4[tid]        = s_out4[tid];
        og4[tid + NTHR] = s_out4[tid + NTHR];
    }
}

extern "C" void kernel_launch(void* const* d_in, const int* in_sizes, int n_in,
                              void* d_out, int out_size, void* d_ws, size_t ws_size,
                              hipStream_t stream) {
    const float* x       = (const float*)d_in[0];
    const int*   lengths = (const int*)  d_in[1];
    // d_in[2] = out_lengths scalar (compile-time 64)
    const float* Wm = (const float*)d_in[3];
    const float* bm = (const float*)d_in[4];
    const float* W1 = (const float*)d_in[5];
    const float* b1 = (const float*)d_in[6];
    const float* W2 = (const float*)d_in[7];
    const float* b2 = (const float*)d_in[8];
    const float* Wo = (const float*)d_in[9];
    const float* bo = (const float*)d_in[10];
    float* out = (float*)d_out;

    delayrnn_kernel<<<BATCH, NTHR, 0, stream>>>(
        x, lengths, Wm, bm, W1, b1, W2, b2, Wo, bo, out);
}